// Round 11
// baseline (2822.220 us; speedup 1.0000x reference)
//
#include <hip/hip_runtime.h>
#include <math.h>

// All-fp32 contract (per reference + scaffold: float32 inputs -> const float*,
// float32 output -> float*). Single kernel symbol, phase-switched; scalar code
// only (no bf16, no ext_vectors, no MFMA, no shuffles, no helpers).
// B=2, T=2048, D=1024, NH=16, NKV=4, HD=64, WIN=128, M=B*T=4096.
//
// ws layout (floats), 48 MB total (< 52 MB proven safe by round 1):
//   O  at       0  (4,194,304 f)  attention out  [4096 x 1024]
//   Qr at 4194304  (4,194,304 f)  [2,16,2048,64]   (overlaid by H after P2)
//   Kr at 8388608  (1,048,576 f)  [2,4,2048,64]
//   Vr at 9437184  (1,048,576 f)  [2,4,2048,64]
//   H  at 4194304  (8,388,608 f)  [4096 x 2048] FFN1 chunk (reuses Qr/Kr/Vr)
//
// Phases (7 launches, one stream, order-guaranteed):
//  0: QKV GEMM 4096x1536x1024, scatter to Qr/Kr/Vr
//  1: RoPE in place on Qr, Kr
//  2: windowed attention, one thread per (b,h,qi) -> O
//  3: FFN1 chunk c: H = silu(O @ W1[c*2048 .. +2048)^T)   (c = 0,1)
//  4: FFN2 chunk c: out (=|+=) H @ W2[:, c*2048 .. +2048)^T

__global__ __launch_bounds__(256) void MultiAttention_60722247631706_kernel(
    const float* x, const float* Wq, const float* Wk, const float* Wv,
    const float* W1, const float* W2, float* out, float* ws,
    int phase, int chunk)
{
    __shared__ float As[64][17];
    __shared__ float Bs[64][17];

    float* O  = ws;
    float* Qr = ws + 4194304;
    float* Kr = ws + 8388608;
    float* Vr = ws + 9437184;
    float* H  = ws + 4194304;

    const int tid = threadIdx.x;

    if (phase == 1) {                      // ---- RoPE (2,621,440 threads)
        int idx = blockIdx.x * 256 + tid;
        float* base;
        int i, t;
        if (idx < 2097152) {               // Q: 32 bh * 2048 t * 32 i
            i = idx & 31; t = (idx >> 5) & 2047;
            base = Qr + ((size_t)(idx >> 16) * 2048 + t) * 64;
        } else {
            idx -= 2097152;                // K: 8 bh * 2048 t * 32 i
            i = idx & 31; t = (idx >> 5) & 2047;
            base = Kr + ((size_t)(idx >> 16) * 2048 + t) * 64;
        }
        const float inv = powf(10000.f, -(float)i / 32.f);
        const float c = cosf((float)t * inv), s = sinf((float)t * inv);
        const float x1 = base[i], x2 = base[i + 32];
        base[i]      = x1 * c - x2 * s;
        base[i + 32] = x1 * s + x2 * c;
        return;
    }

    if (phase == 2) {                      // ---- attention (65,536 threads)
        const int gw  = blockIdx.x * 256 + tid;
        const int qi  = gw & 2047;
        const int h   = (gw >> 11) & 15;
        const int b   = gw >> 15;
        const int kvh = h >> 2;

        const float* qp = Qr + (((size_t)(b * 16 + h)) * 2048 + qi) * 64;
        const float* Kb = Kr + ((size_t)(b * 4 + kvh)) * 2048 * 64;
        const float* Vb = Vr + ((size_t)(b * 4 + kvh)) * 2048 * 64;

        float q[64];
        for (int d = 0; d < 64; ++d) q[d] = qp[d];

        const int jlo = qi > 127 ? qi - 127 : 0;
        const int cnt = qi - jlo + 1;

        float mx = -1e30f;
        for (int jj = 0; jj < cnt; ++jj) {
            const float* kp = Kb + (size_t)(jlo + jj) * 64;
            float s = 0.f;
            for (int d = 0; d < 64; ++d) s += q[d] * kp[d];
            s *= 0.125f;
            mx = fmaxf(mx, s);
        }
        float o[64];
        for (int d = 0; d < 64; ++d) o[d] = 0.f;
        float sum = 0.f;
        for (int jj = 0; jj < cnt; ++jj) {
            const float* kp = Kb + (size_t)(jlo + jj) * 64;
            float s = 0.f;
            for (int d = 0; d < 64; ++d) s += q[d] * kp[d];
            const float p = expf(s * 0.125f - mx);
            sum += p;
            const float* vp = Vb + (size_t)(jlo + jj) * 64;
            for (int d = 0; d < 64; ++d) o[d] += p * vp[d];
        }
        const float rs = 1.f / sum;
        float* op = O + ((size_t)(b * 2048 + qi)) * 1024 + h * 64;
        for (int d = 0; d < 64; ++d) op[d] = o[d] * rs;
        return;
    }

    // ---- phases 0/3/4: tiled 64x64 GEMM, C[M,N] = A[M,K] @ Brow[N,K]^T
    const float* A; int lda, N, K, ldc;
    if (phase == 0)      { A = x; lda = 1024; N = 1536; K = 1024; ldc = 0;    }
    else if (phase == 3) { A = O; lda = 1024; N = 2048; K = 1024; ldc = 2048; }
    else                 { A = H; lda = 2048; N = 1024; K = 2048; ldc = 1024; }

    const int ntiles_n = N >> 6;
    const int tm = blockIdx.x / ntiles_n;
    const int tn = blockIdx.x % ntiles_n;
    const int tx = tid & 15;
    const int ty = tid >> 4;

    float acc[4][4];
    for (int i = 0; i < 4; ++i)
        for (int j = 0; j < 4; ++j) acc[i][j] = 0.f;

    for (int k0 = 0; k0 < K; k0 += 16) {
        for (int q4 = 0; q4 < 4; ++q4) {
            const int idx = tid * 4 + q4;
            const int r = idx >> 4;        // 0..63
            const int c = idx & 15;        // 0..15
            As[r][c] = A[(size_t)(tm * 64 + r) * lda + k0 + c];
            const int nr = tn * 64 + r;
            const float* brow;
            if (phase == 0) {
                if (nr < 1024)      brow = Wq + (size_t)nr * 1024;
                else if (nr < 1280) brow = Wk + (size_t)(nr - 1024) * 1024;
                else                brow = Wv + (size_t)(nr - 1280) * 1024;
            } else if (phase == 3) {
                brow = W1 + (size_t)(chunk * 2048 + nr) * 1024;
            } else {
                brow = W2 + (size_t)nr * 4096 + chunk * 2048;
            }
            Bs[r][c] = brow[k0 + c];
        }
        __syncthreads();
        for (int kk = 0; kk < 16; ++kk) {
            float a0 = As[ty * 4 + 0][kk], a1 = As[ty * 4 + 1][kk];
            float a2 = As[ty * 4 + 2][kk], a3 = As[ty * 4 + 3][kk];
            float b0 = Bs[tx * 4 + 0][kk], b1 = Bs[tx * 4 + 1][kk];
            float b2 = Bs[tx * 4 + 2][kk], b3 = Bs[tx * 4 + 3][kk];
            acc[0][0] += a0 * b0; acc[0][1] += a0 * b1;
            acc[0][2] += a0 * b2; acc[0][3] += a0 * b3;
            acc[1][0] += a1 * b0; acc[1][1] += a1 * b1;
            acc[1][2] += a1 * b2; acc[1][3] += a1 * b3;
            acc[2][0] += a2 * b0; acc[2][1] += a2 * b1;
            acc[2][2] += a2 * b2; acc[2][3] += a2 * b3;
            acc[3][0] += a3 * b0; acc[3][1] += a3 * b1;
            acc[3][2] += a3 * b2; acc[3][3] += a3 * b3;
        }
        __syncthreads();
    }

    for (int i = 0; i < 4; ++i) {
        const int m = tm * 64 + ty * 4 + i;
        for (int j = 0; j < 4; ++j) {
            const int n = tn * 64 + tx * 4 + j;
            const float v = acc[i][j];
            if (phase == 0) {
                const int b = m >> 11, t = m & 2047;
                if (n < 1024) {
                    Qr[(((size_t)(b * 16 + (n >> 6))) * 2048 + t) * 64 + (n & 63)] = v;
                } else if (n < 1280) {
                    Kr[(((size_t)(b * 4 + ((n - 1024) >> 6))) * 2048 + t) * 64 + (n & 63)] = v;
                } else {
                    Vr[(((size_t)(b * 4 + ((n - 1280) >> 6))) * 2048 + t) * 64 + (n & 63)] = v;
                }
            } else if (phase == 3) {
                H[(size_t)m * 2048 + n] = v / (1.f + expf(-v));   // silu
            } else {
                if (chunk == 0) out[(size_t)m * 1024 + n] = v;
                else            out[(size_t)m * 1024 + n] += v;
            }
        }
    }
}

extern "C" void kernel_launch(void* const* d_in, const int* in_sizes, int n_in,
                              void* d_out, int out_size, void* d_ws, size_t ws_size,
                              hipStream_t stream)
{
    const float* x  = (const float*)d_in[0];
    const float* Wq = (const float*)d_in[1];
    const float* Wk = (const float*)d_in[2];
    const float* Wv = (const float*)d_in[3];
    const float* W1 = (const float*)d_in[4];
    const float* W2 = (const float*)d_in[5];
    float* out = (float*)d_out;
    float* ws  = (float*)d_ws;

    // P0: QKV GEMM: (4096/64)*(1536/64) = 64*24 = 1536 blocks
    MultiAttention_60722247631706_kernel<<<1536, 256, 0, stream>>>(
        x, Wq, Wk, Wv, W1, W2, out, ws, 0, 0);
    // P1: RoPE: 2,621,440 threads / 256 = 10240 blocks
    MultiAttention_60722247631706_kernel<<<10240, 256, 0, stream>>>(
        x, Wq, Wk, Wv, W1, W2, out, ws, 1, 0);
    // P2: attention: 65,536 threads / 256 = 256 blocks
    MultiAttention_60722247631706_kernel<<<256, 256, 0, stream>>>(
        x, Wq, Wk, Wv, W1, W2, out, ws, 2, 0);
    // P3/P4 chunks: FFN1 64*32 = 2048 blocks; FFN2 64*16 = 1024 blocks
    MultiAttention_60722247631706_kernel<<<2048, 256, 0, stream>>>(
        x, Wq, Wk, Wv, W1, W2, out, ws, 3, 0);
    MultiAttention_60722247631706_kernel<<<1024, 256, 0, stream>>>(
        x, Wq, Wk, Wv, W1, W2, out, ws, 4, 0);
    MultiAttention_60722247631706_kernel<<<2048, 256, 0, stream>>>(
        x, Wq, Wk, Wv, W1, W2, out, ws, 3, 1);
    MultiAttention_60722247631706_kernel<<<1024, 256, 0, stream>>>(
        x, Wq, Wk, Wv, W1, W2, out, ws, 4, 1);
}

// Round 12
// 717.290 us; speedup vs baseline: 3.9346x; 3.9346x over previous
//
#include <hip/hip_runtime.h>
#include <math.h>

// fp32 in / fp32 out (round-11-verified contract). Single kernel symbol,
// phase-switched, round-11 ws layout (48 MB). GEMM phases upgraded to MFMA
// bf16 (fp32 staged to LDS as bf16, fp32 accumulate); attention upgraded to
// one wave per query. B=2,T=2048,D=1024,NH=16,NKV=4,HD=64,WIN=128,M=4096.
//
// ws (floats): O@0 (4.19M) | Qr@4194304 (4.19M) | Kr@8388608 (1.05M) |
//              Vr@9437184 (1.05M) | H@4194304 (8.39M, overlays QKV after P2)
// Phases: 0 QKV-GEMM(scatter) | 1 RoPE | 2 attention | 3 FFN1 chunk (silu)
//         | 4 FFN2 chunk (=/+= out).  7 launches total, same as round 11.
//
// MFMA fragment layouts (HW-verified m89/m91):
//   A[m=lane&15][k=(lane>>4)*8+j], B[n=lane&15][k=same]
//   D: col(n)=lane&15, row(m)=(lane>>4)*4+reg

typedef __bf16 bf16x8 __attribute__((ext_vector_type(8)));
typedef float  f32x4  __attribute__((ext_vector_type(4)));

__global__ __launch_bounds__(256) void MultiAttention_60722247631706_kernel(
    const float* x, const float* Wq, const float* Wk, const float* Wv,
    const float* W1, const float* W2, float* out, float* ws,
    int phase, int chunk)
{
    float* O  = ws;
    float* Qr = ws + 4194304;
    float* Kr = ws + 8388608;
    float* Vr = ws + 9437184;
    float* H  = ws + 4194304;

    const int tid = threadIdx.x;

    if (phase == 1) {                      // ---- RoPE (2,621,440 threads)
        int idx = blockIdx.x * 256 + tid;
        float* base;
        int i, t;
        if (idx < 2097152) {               // Q: 32 bh * 2048 t * 32 i
            i = idx & 31; t = (idx >> 5) & 2047;
            base = Qr + ((size_t)(idx >> 16) * 2048 + t) * 64;
        } else {
            idx -= 2097152;                // K: 8 bh * 2048 t * 32 i
            i = idx & 31; t = (idx >> 5) & 2047;
            base = Kr + ((size_t)(idx >> 16) * 2048 + t) * 64;
        }
        const float inv = powf(10000.f, -(float)i / 32.f);
        const float c = cosf((float)t * inv), s = sinf((float)t * inv);
        const float x1 = base[i], x2 = base[i + 32];
        base[i]      = x1 * c - x2 * s;
        base[i + 32] = x1 * s + x2 * c;
        return;
    }

    if (phase == 2) {                      // ---- attention: 1 wave / query
        __shared__ float qs[4][64];
        __shared__ float ps[4][128];
        const int w    = tid >> 6;
        const int lane = tid & 63;
        const int gw   = blockIdx.x * 4 + w;   // 0..65535
        const int qi   = gw & 2047;
        const int h    = (gw >> 11) & 15;
        const int b    = gw >> 15;
        const int kvh  = h >> 2;

        qs[w][lane] = Qr[(((size_t)(b * 16 + h)) * 2048 + qi) * 64 + lane];
        __syncthreads();

        const int jlo = qi > 127 ? qi - 127 : 0;
        const int cnt = qi - jlo + 1;          // 1..128
        const float* Kb = Kr + ((size_t)(b * 4 + kvh)) * 2048 * 64;

        float s0 = -1e30f, s1 = -1e30f;
        for (int sidx = 0; sidx < 2; ++sidx) {
            const int jj = lane + sidx * 64;
            if (jj < cnt) {
                const float* kp = Kb + (size_t)(jlo + jj) * 64;
                float acc = 0.f;
                for (int d = 0; d < 64; ++d) acc += kp[d] * qs[w][d];
                if (sidx == 0) s0 = acc * 0.125f; else s1 = acc * 0.125f;
            }
        }
        float mx = fmaxf(s0, s1);
        for (int off = 32; off; off >>= 1) mx = fmaxf(mx, __shfl_xor(mx, off));
        const float p0 = (s0 > -1e29f) ? expf(s0 - mx) : 0.f;
        const float p1 = (s1 > -1e29f) ? expf(s1 - mx) : 0.f;
        float sum = p0 + p1;
        for (int off = 32; off; off >>= 1) sum += __shfl_xor(sum, off);
        ps[w][lane]      = p0;
        ps[w][lane + 64] = p1;
        __syncthreads();

        const float rs = 1.f / sum;
        const float* Vb = Vr + ((size_t)(b * 4 + kvh)) * 2048 * 64 + lane;
        float acc = 0.f;
        for (int jj = 0; jj < cnt; ++jj)
            acc += ps[w][jj] * Vb[(size_t)(jlo + jj) * 64];
        O[(((size_t)(b * 2048 + qi)) * 1024) + h * 64 + lane] = acc * rs;
        return;
    }

    // ---- phases 0/3/4: MFMA GEMM, C[M,N]=A[M,K]@Brow[N,K]^T, 64x64/block
    __shared__ __bf16 As[64][40];     // 32 k + 8 pad (bank stride 20)
    __shared__ __bf16 Bs[64][40];

    const float* A; int lda, K;
    int ntn;
    if (phase == 0)      { A = x; lda = 1024; K = 1024; ntn = 24; }
    else if (phase == 3) { A = O; lda = 1024; K = 1024; ntn = 32; }
    else                 { A = H; lda = 2048; K = 2048; ntn = 16; }

    const int tm   = blockIdx.x / ntn;
    const int tn   = blockIdx.x % ntn;
    const int wv   = tid >> 6;
    const int lane = tid & 63;
    const int l16  = lane & 15;
    const int quad = lane >> 4;

    // staging assignment: thread -> (row 0..63, kcol base 0..24 step 8)
    const int srow = tid >> 2;
    const int scol = (tid & 3) * 8;

    const float* ap = A + (size_t)(tm * 64 + srow) * lda + scol;
    const int nr = tn * 64 + srow;
    const float* bp;
    if (phase == 0) {
        if (nr < 1024)      bp = Wq + (size_t)nr * 1024;
        else if (nr < 1280) bp = Wk + (size_t)(nr - 1024) * 1024;
        else                bp = Wv + (size_t)(nr - 1280) * 1024;
    } else if (phase == 3) {
        bp = W1 + (size_t)(chunk * 2048 + nr) * 1024;
    } else {
        bp = W2 + (size_t)nr * 4096 + chunk * 2048;
    }
    bp += scol;

    f32x4 ac0 = {0.f, 0.f, 0.f, 0.f};
    f32x4 ac1 = {0.f, 0.f, 0.f, 0.f};
    f32x4 ac2 = {0.f, 0.f, 0.f, 0.f};
    f32x4 ac3 = {0.f, 0.f, 0.f, 0.f};

    for (int k0 = 0; k0 < K; k0 += 32) {
#pragma unroll
        for (int j = 0; j < 8; ++j) {
            As[srow][scol + j] = (__bf16)ap[k0 + j];
            Bs[srow][scol + j] = (__bf16)bp[k0 + j];
        }
        __syncthreads();
        const bf16x8 af = *(const bf16x8*)&As[wv * 16 + l16][quad * 8];
        const bf16x8 b0 = *(const bf16x8*)&Bs[l16     ][quad * 8];
        const bf16x8 b1 = *(const bf16x8*)&Bs[16 + l16][quad * 8];
        const bf16x8 b2 = *(const bf16x8*)&Bs[32 + l16][quad * 8];
        const bf16x8 b3 = *(const bf16x8*)&Bs[48 + l16][quad * 8];
        ac0 = __builtin_amdgcn_mfma_f32_16x16x32_bf16(af, b0, ac0, 0, 0, 0);
        ac1 = __builtin_amdgcn_mfma_f32_16x16x32_bf16(af, b1, ac1, 0, 0, 0);
        ac2 = __builtin_amdgcn_mfma_f32_16x16x32_bf16(af, b2, ac2, 0, 0, 0);
        ac3 = __builtin_amdgcn_mfma_f32_16x16x32_bf16(af, b3, ac3, 0, 0, 0);
        __syncthreads();
    }

    // D layout: m = tm*64 + wv*16 + quad*4 + r ; n = tn*64 + c*16 + l16
#pragma unroll
    for (int c = 0; c < 4; ++c) {
        const int n = tn * 64 + c * 16 + l16;
#pragma unroll
        for (int r = 0; r < 4; ++r) {
            const int m = tm * 64 + wv * 16 + quad * 4 + r;
            float v;
            if (c == 0) v = ac0[r];
            else if (c == 1) v = ac1[r];
            else if (c == 2) v = ac2[r];
            else v = ac3[r];
            if (phase == 0) {
                const int b = m >> 11, t = m & 2047;
                if (n < 1024) {
                    Qr[(((size_t)(b * 16 + (n >> 6))) * 2048 + t) * 64 + (n & 63)] = v;
                } else if (n < 1280) {
                    Kr[(((size_t)(b * 4 + ((n - 1024) >> 6))) * 2048 + t) * 64 + (n & 63)] = v;
                } else {
                    Vr[(((size_t)(b * 4 + ((n - 1280) >> 6))) * 2048 + t) * 64 + (n & 63)] = v;
                }
            } else if (phase == 3) {
                H[(size_t)m * 2048 + n] = v / (1.f + expf(-v));   // silu
            } else {
                if (chunk == 0) out[(size_t)m * 1024 + n] = v;
                else            out[(size_t)m * 1024 + n] += v;
            }
        }
    }
}

extern "C" void kernel_launch(void* const* d_in, const int* in_sizes, int n_in,
                              void* d_out, int out_size, void* d_ws, size_t ws_size,
                              hipStream_t stream)
{
    const float* x  = (const float*)d_in[0];
    const float* Wq = (const float*)d_in[1];
    const float* Wk = (const float*)d_in[2];
    const float* Wv = (const float*)d_in[3];
    const float* W1 = (const float*)d_in[4];
    const float* W2 = (const float*)d_in[5];
    float* out = (float*)d_out;
    float* ws  = (float*)d_ws;

    // P0: QKV GEMM: 64*24 = 1536 blocks
    MultiAttention_60722247631706_kernel<<<1536, 256, 0, stream>>>(
        x, Wq, Wk, Wv, W1, W2, out, ws, 0, 0);
    // P1: RoPE: 10240 blocks
    MultiAttention_60722247631706_kernel<<<10240, 256, 0, stream>>>(
        x, Wq, Wk, Wv, W1, W2, out, ws, 1, 0);
    // P2: attention: 65536 waves / 4 per block = 16384 blocks
    MultiAttention_60722247631706_kernel<<<16384, 256, 0, stream>>>(
        x, Wq, Wk, Wv, W1, W2, out, ws, 2, 0);
    // P3/P4 chunks: FFN1 64*32 = 2048 blocks; FFN2 64*16 = 1024 blocks
    MultiAttention_60722247631706_kernel<<<2048, 256, 0, stream>>>(
        x, Wq, Wk, Wv, W1, W2, out, ws, 3, 0);
    MultiAttention_60722247631706_kernel<<<1024, 256, 0, stream>>>(
        x, Wq, Wk, Wv, W1, W2, out, ws, 4, 0);
    MultiAttention_60722247631706_kernel<<<2048, 256, 0, stream>>>(
        x, Wq, Wk, Wv, W1, W2, out, ws, 3, 1);
    MultiAttention_60722247631706_kernel<<<1024, 256, 0, stream>>>(
        x, Wq, Wk, Wv, W1, W2, out, ws, 4, 1);
}

// Round 13
// 553.584 us; speedup vs baseline: 5.0981x; 1.2957x over previous
//
#include <hip/hip_runtime.h>
#include <math.h>

// fp32 in / fp32 out (round-11-verified). Single kernel symbol, phase-switched.
// B=2,T=2048,D=1024,NH=16,NKV=4,HD=64,WIN=128,M=4096.
// ws (floats): O@0 (4.19M) | Qr@4194304 | Kr@8388608 | Vr@9437184 |
//              H@4194304 (overlays QKV region after attention)
// Phases (6 launches): 0 QKV-GEMM + fused RoPE (scatter) | 2 attention
//   (block = b,kvh,qi; 4 waves = 4 GQA heads; K/V window staged in LDS bf16)
//   | 3 FFN1 chunk (silu) | 4 FFN2 chunk (=/+= out).
// Dynamic LDS: GEMM 18432 B (As/Bs 64x72 bf16); attention 36864 B
//   (qs 4x64 f32 | ps 4x128 f32 | Ks 128x66 bf16 | Vs 128x66 bf16).
// MFMA layouts (HW-verified m89/m91): A[m=lane&15][k=(lane>>4)*8+j],
//   B[n=lane&15][k=same], D: col=lane&15, row=(lane>>4)*4+reg.

typedef __bf16 bf16x8 __attribute__((ext_vector_type(8)));
typedef float  f32x4  __attribute__((ext_vector_type(4)));

extern __shared__ __align__(16) char smem[];

__global__ __launch_bounds__(256) void MultiAttention_60722247631706_kernel(
    const float* x, const float* Wq, const float* Wk, const float* Wv,
    const float* W1, const float* W2, float* out, float* ws,
    int phase, int chunk)
{
    float* O  = ws;
    float* Qr = ws + 4194304;
    float* Kr = ws + 8388608;
    float* Vr = ws + 9437184;
    float* H  = ws + 4194304;

    const int tid = threadIdx.x;

    if (phase == 2) {   // ---- attention: block=(b,kvh,qi), wave=head
        float*  qs = (float*)smem;            // [4][64]
        float*  ps = qs + 256;                // [4][128]
        __bf16* Ks = (__bf16*)(ps + 512);     // [128][66]
        __bf16* Vs = Ks + 128 * 66;           // [128][66]

        const int qi   = blockIdx.x & 2047;
        const int kvb  = blockIdx.x >> 11;    // 0..7
        const int kvh  = kvb & 3;
        const int b    = kvb >> 2;
        const int w    = tid >> 6;
        const int lane = tid & 63;
        const int h    = kvh * 4 + w;

        const int jlo = qi > 127 ? qi - 127 : 0;
        const int cnt = qi - jlo + 1;         // 1..128

        const float* Kb = Kr + ((size_t)(b * 4 + kvh)) * 2048 * 64 + (size_t)jlo * 64;
        const float* Vb = Vr + ((size_t)(b * 4 + kvh)) * 2048 * 64 + (size_t)jlo * 64;

        // stage K/V window (cnt rows x 64) -> LDS bf16, row stride 66
        for (int i = tid; i < cnt * 16; i += 256) {
            const int r  = i >> 4;
            const int c4 = (i & 15) * 4;
            const f32x4 kv = *(const f32x4*)(Kb + r * 64 + c4);
            const f32x4 vv = *(const f32x4*)(Vb + r * 64 + c4);
            __bf16* kd = Ks + r * 66 + c4;
            __bf16* vd = Vs + r * 66 + c4;
            kd[0] = (__bf16)kv[0]; kd[1] = (__bf16)kv[1];
            kd[2] = (__bf16)kv[2]; kd[3] = (__bf16)kv[3];
            vd[0] = (__bf16)vv[0]; vd[1] = (__bf16)vv[1];
            vd[2] = (__bf16)vv[2]; vd[3] = (__bf16)vv[3];
        }
        qs[w * 64 + lane] = Qr[(((size_t)(b * 16 + h)) * 2048 + qi) * 64 + lane];
        __syncthreads();

        float s0 = -1e30f, s1 = -1e30f;
        if (lane < cnt) {
            const __bf16* kp = Ks + lane * 66;
            float acc = 0.f;
#pragma unroll 8
            for (int d = 0; d < 64; ++d) acc += (float)kp[d] * qs[w * 64 + d];
            s0 = acc * 0.125f;
        }
        if (lane + 64 < cnt) {
            const __bf16* kp = Ks + (lane + 64) * 66;
            float acc = 0.f;
#pragma unroll 8
            for (int d = 0; d < 64; ++d) acc += (float)kp[d] * qs[w * 64 + d];
            s1 = acc * 0.125f;
        }

        float mx = fmaxf(s0, s1);
        for (int off = 32; off; off >>= 1) mx = fmaxf(mx, __shfl_xor(mx, off));
        const float p0 = (s0 > -1e29f) ? expf(s0 - mx) : 0.f;
        const float p1 = (s1 > -1e29f) ? expf(s1 - mx) : 0.f;
        float sum = p0 + p1;
        for (int off = 32; off; off >>= 1) sum += __shfl_xor(sum, off);
        ps[w * 128 + lane]      = p0;
        ps[w * 128 + 64 + lane] = p1;
        __syncthreads();

        const float rs = 1.f / sum;
        float acc = 0.f;
#pragma unroll 4
        for (int jj = 0; jj < cnt; ++jj)
            acc += ps[w * 128 + jj] * (float)Vs[jj * 66 + lane];
        O[((size_t)(b * 2048 + qi)) * 1024 + h * 64 + lane] = acc * rs;
        return;
    }

    // ---- phases 0/3/4: MFMA GEMM, C[M,N]=A[M,K]@Brow[N,K]^T, 64x64/block
    __bf16* As = (__bf16*)smem;       // [64][72]
    __bf16* Bs = As + 64 * 72;        // [64][72]

    const float* A; int lda, K, ntn;
    if (phase == 0)      { A = x; lda = 1024; K = 1024; ntn = 24; }
    else if (phase == 3) { A = O; lda = 1024; K = 1024; ntn = 32; }
    else                 { A = H; lda = 2048; K = 2048; ntn = 16; }

    const int tm   = blockIdx.x / ntn;
    const int tn   = blockIdx.x % ntn;
    const int wv   = tid >> 6;
    const int lane = tid & 63;
    const int l16  = lane & 15;
    const int quad = lane >> 4;

    // staging: thread -> row = tid>>2, 16 cols starting at (tid&3)*16
    const int srow = tid >> 2;
    const int sc0  = (tid & 3) * 16;

    const float* ap = A + (size_t)(tm * 64 + srow) * lda + sc0;
    const int nr = tn * 64 + srow;
    const float* bp;
    if (phase == 0) {
        if (nr < 1024)      bp = Wq + (size_t)nr * 1024;
        else if (nr < 1280) bp = Wk + (size_t)(nr - 1024) * 1024;
        else                bp = Wv + (size_t)(nr - 1280) * 1024;
    } else if (phase == 3) {
        bp = W1 + (size_t)(chunk * 2048 + nr) * 1024;
    } else {
        bp = W2 + (size_t)nr * 4096 + chunk * 2048;
    }
    bp += sc0;

    f32x4 ac0 = {0.f, 0.f, 0.f, 0.f};
    f32x4 ac1 = {0.f, 0.f, 0.f, 0.f};
    f32x4 ac2 = {0.f, 0.f, 0.f, 0.f};
    f32x4 ac3 = {0.f, 0.f, 0.f, 0.f};

    for (int k0 = 0; k0 < K; k0 += 64) {
#pragma unroll
        for (int i = 0; i < 4; ++i) {
            const f32x4 av = *(const f32x4*)(ap + k0 + i * 4);
            const f32x4 bv = *(const f32x4*)(bp + k0 + i * 4);
            __bf16* ad = As + srow * 72 + sc0 + i * 4;
            __bf16* bd = Bs + srow * 72 + sc0 + i * 4;
            ad[0] = (__bf16)av[0]; ad[1] = (__bf16)av[1];
            ad[2] = (__bf16)av[2]; ad[3] = (__bf16)av[3];
            bd[0] = (__bf16)bv[0]; bd[1] = (__bf16)bv[1];
            bd[2] = (__bf16)bv[2]; bd[3] = (__bf16)bv[3];
        }
        __syncthreads();
#pragma unroll
        for (int kk = 0; kk < 2; ++kk) {
            const int ko = kk * 32 + quad * 8;
            const bf16x8 af = *(const bf16x8*)(As + (wv * 16 + l16) * 72 + ko);
            const bf16x8 b0 = *(const bf16x8*)(Bs + (l16)      * 72 + ko);
            const bf16x8 b1 = *(const bf16x8*)(Bs + (16 + l16) * 72 + ko);
            const bf16x8 b2 = *(const bf16x8*)(Bs + (32 + l16) * 72 + ko);
            const bf16x8 b3 = *(const bf16x8*)(Bs + (48 + l16) * 72 + ko);
            ac0 = __builtin_amdgcn_mfma_f32_16x16x32_bf16(af, b0, ac0, 0, 0, 0);
            ac1 = __builtin_amdgcn_mfma_f32_16x16x32_bf16(af, b1, ac1, 0, 0, 0);
            ac2 = __builtin_amdgcn_mfma_f32_16x16x32_bf16(af, b2, ac2, 0, 0, 0);
            ac3 = __builtin_amdgcn_mfma_f32_16x16x32_bf16(af, b3, ac3, 0, 0, 0);
        }
        __syncthreads();
    }

    // D: m = tm*64 + wv*16 + quad*4 + r ; n = tn*64 + c*16 + l16
    if (phase == 0) {
        // Fused RoPE: lane holds d and d+32 as pairs (ac0,ac2) i=l16 and
        // (ac1,ac3) i=16+l16. Rotate for Q tiles (tn<16) and K tiles (16..19).
        const int rot = (tn < 20);
        const float inv1 = powf(10000.f, -(float)l16 / 32.f);
        const float inv2 = powf(10000.f, -(float)(16 + l16) / 32.f);
#pragma unroll
        for (int r = 0; r < 4; ++r) {
            const int m = tm * 64 + wv * 16 + quad * 4 + r;
            const int bb = m >> 11, t = m & 2047;
            float v0 = ac0[r], v1 = ac1[r], v2 = ac2[r], v3 = ac3[r];
            if (rot) {
                const float a1 = (float)t * inv1, a2 = (float)t * inv2;
                const float c1 = cosf(a1), s1 = sinf(a1);
                const float c2 = cosf(a2), s2 = sinf(a2);
                const float n0 = v0 * c1 - v2 * s1;
                const float n2 = v0 * s1 + v2 * c1;
                const float n1 = v1 * c2 - v3 * s2;
                const float n3 = v1 * s2 + v3 * c2;
                v0 = n0; v1 = n1; v2 = n2; v3 = n3;
            }
#pragma unroll
            for (int c = 0; c < 4; ++c) {
                const int n = tn * 64 + c * 16 + l16;
                const float v = (c == 0) ? v0 : (c == 1) ? v1 : (c == 2) ? v2 : v3;
                if (n < 1024) {
                    Qr[(((size_t)(bb * 16 + (n >> 6))) * 2048 + t) * 64 + (n & 63)] = v;
                } else if (n < 1280) {
                    Kr[(((size_t)(bb * 4 + ((n - 1024) >> 6))) * 2048 + t) * 64 + (n & 63)] = v;
                } else {
                    Vr[(((size_t)(bb * 4 + ((n - 1280) >> 6))) * 2048 + t) * 64 + (n & 63)] = v;
                }
            }
        }
    } else {
#pragma unroll
        for (int c = 0; c < 4; ++c) {
            const int n = tn * 64 + c * 16 + l16;
#pragma unroll
            for (int r = 0; r < 4; ++r) {
                const int m = tm * 64 + wv * 16 + quad * 4 + r;
                const float v = (c == 0) ? ac0[r] : (c == 1) ? ac1[r]
                              : (c == 2) ? ac2[r] : ac3[r];
                if (phase == 3) {
                    H[(size_t)m * 2048 + n] = v / (1.f + expf(-v));   // silu
                } else {
                    if (chunk == 0) out[(size_t)m * 1024 + n] = v;
                    else            out[(size_t)m * 1024 + n] += v;
                }
            }
        }
    }
}

extern "C" void kernel_launch(void* const* d_in, const int* in_sizes, int n_in,
                              void* d_out, int out_size, void* d_ws, size_t ws_size,
                              hipStream_t stream)
{
    const float* x  = (const float*)d_in[0];
    const float* Wq = (const float*)d_in[1];
    const float* Wk = (const float*)d_in[2];
    const float* Wv = (const float*)d_in[3];
    const float* W1 = (const float*)d_in[4];
    const float* W2 = (const float*)d_in[5];
    float* out = (float*)d_out;
    float* ws  = (float*)d_ws;

    const int GEMM_LDS = 2 * 64 * 72 * 2;   // 18432 B
    const int ATTN_LDS = 256 * 4 + 512 * 4 + 2 * 128 * 66 * 2;  // 36864 B

    // P0: QKV GEMM + fused RoPE: 64*24 = 1536 blocks
    MultiAttention_60722247631706_kernel<<<1536, 256, GEMM_LDS, stream>>>(
        x, Wq, Wk, Wv, W1, W2, out, ws, 0, 0);
    // P2: attention: (b,kvh,qi) = 2*4*2048 = 16384 blocks
    MultiAttention_60722247631706_kernel<<<16384, 256, ATTN_LDS, stream>>>(
        x, Wq, Wk, Wv, W1, W2, out, ws, 2, 0);
    // P3/P4 chunks: FFN1 64*32 = 2048 blocks; FFN2 64*16 = 1024 blocks
    MultiAttention_60722247631706_kernel<<<2048, 256, GEMM_LDS, stream>>>(
        x, Wq, Wk, Wv, W1, W2, out, ws, 3, 0);
    MultiAttention_60722247631706_kernel<<<1024, 256, GEMM_LDS, stream>>>(
        x, Wq, Wk, Wv, W1, W2, out, ws, 4, 0);
    MultiAttention_60722247631706_kernel<<<2048, 256, GEMM_LDS, stream>>>(
        x, Wq, Wk, Wv, W1, W2, out, ws, 3, 1);
    MultiAttention_60722247631706_kernel<<<1024, 256, GEMM_LDS, stream>>>(
        x, Wq, Wk, Wv, W1, W2, out, ws, 4, 1);
}